// Round 2
// baseline (983.499 us; speedup 1.0000x reference)
//
#include <hip/hip_runtime.h>

#define D 64
#define TSCAN 1024
#define NB_SCAN 98   // ceil(100000/1024); works for any n <= NB_SCAN*TSCAN

__device__ __forceinline__ float bcast(float v, int l) {
    return __uint_as_float(__builtin_amdgcn_readlane(__float_as_uint(v), l));
}

// ---------- CSR build ----------
__global__ void __launch_bounds__(256) hist_kernel(
    const int* __restrict__ dst, int* __restrict__ cnt, int E)
{
    int t = blockIdx.x * blockDim.x + threadIdx.x;
    int st = gridDim.x * blockDim.x;
    for (int e = t; e < E; e += st) atomicAdd(&cnt[dst[e]], 1);
}

__global__ void __launch_bounds__(TSCAN) partial_kernel(
    const int* __restrict__ cnt, int* __restrict__ partials, int n)
{
    __shared__ int red[TSCAN];
    int i = blockIdx.x * TSCAN + threadIdx.x;
    red[threadIdx.x] = (i < n) ? cnt[i] : 0;
    __syncthreads();
    for (int off = TSCAN / 2; off > 0; off >>= 1) {
        if (threadIdx.x < off) red[threadIdx.x] += red[threadIdx.x + off];
        __syncthreads();
    }
    if (threadIdx.x == 0) partials[blockIdx.x] = red[0];
}

__global__ void __launch_bounds__(128) scanp_kernel(
    const int* __restrict__ partials, int* __restrict__ blockoff, int nb)
{
    __shared__ int s[128];
    int t = threadIdx.x;
    int orig = (t < nb) ? partials[t] : 0;
    s[t] = orig;
    __syncthreads();
    for (int off = 1; off < 128; off <<= 1) {
        int v = (t >= off) ? s[t - off] : 0;
        __syncthreads();
        s[t] += v;
        __syncthreads();
    }
    if (t < nb) blockoff[t] = s[t] - orig;   // exclusive
}

__global__ void __launch_bounds__(TSCAN) rowptr_kernel(
    const int* __restrict__ cnt, const int* __restrict__ blockoff,
    int* __restrict__ rowptr, int* __restrict__ cursor, int n)
{
    __shared__ int s[TSCAN];
    int b = blockIdx.x;
    int i = b * TSCAN + threadIdx.x;
    int v = (i < n) ? cnt[i] : 0;
    s[threadIdx.x] = v;
    __syncthreads();
    for (int off = 1; off < TSCAN; off <<= 1) {
        int x = (threadIdx.x >= off) ? s[threadIdx.x - off] : 0;
        __syncthreads();
        s[threadIdx.x] += x;
        __syncthreads();
    }
    if (i < n) {
        int excl = blockoff[b] + s[threadIdx.x] - v;
        rowptr[i] = excl;
        cursor[i] = excl;
        if (i == n - 1) rowptr[n] = excl + v;
    }
}

__global__ void __launch_bounds__(256) fill_kernel(
    const int* __restrict__ src, const int* __restrict__ dst,
    int* __restrict__ cursor, int* __restrict__ adj, int E)
{
    int t = blockIdx.x * blockDim.x + threadIdx.x;
    int st = gridDim.x * blockDim.x;
    for (int e = t; e < E; e += st) {
        int p = atomicAdd(&cursor[dst[e]], 1);
        adj[p] = src[e];
    }
}

// ---------- fused SAGE layer: gather-mean + concat-linear (+ optional head) ----------
// Wave per node; lane j owns feature/output channel j.
// Dynamic LDS layout: Wt4[32*64 float4] | bs[64] | (HEAD: wc1t[64*32] w2s[64] bc1s[32] bc2s[2])
template <bool HEAD>
__global__ void __launch_bounds__(512) sage_kernel(
    const float* __restrict__ x,       // [n, 64]
    const int*   __restrict__ rowptr,  // [n+1]
    const int*   __restrict__ adj,     // [E]
    const float* __restrict__ W,       // [64, 128] row-major
    const float* __restrict__ b,       // [64]
    const float* __restrict__ Wc1,     // [32, 64]  (HEAD only)
    const float* __restrict__ bc1,     // [32]
    const float* __restrict__ Wc2,     // [2, 32]
    const float* __restrict__ bc2,     // [2]
    float*       __restrict__ out,     // HEAD ? [n,2] : [n,64]
    int n)
{
    extern __shared__ float smem[];
    float4* Wt4 = (float4*)smem;               // 8192 floats
    float*  Wt  = smem;
    float*  bs  = smem + 8192;                 // 64
    float*  wc1t = bs + 64;                    // 2048 (HEAD)
    float*  w2s  = wc1t + 2048;                // 64
    float*  bc1s = w2s + 64;                   // 32
    float*  bc2s = bc1s + 32;                  // 2

    for (int i = threadIdx.x; i < 64 * 128; i += blockDim.x) {
        int j = i >> 7, k = i & 127;
        Wt[(k >> 2) * 256 + j * 4 + (k & 3)] = W[i];   // Wt4[k4*64+j] = W[j][4k4..]
    }
    if (threadIdx.x < 64) bs[threadIdx.x] = b[threadIdx.x];
    if (HEAD) {
        for (int i = threadIdx.x; i < 32 * 64; i += blockDim.x) {
            int l = i >> 6, k = i & 63;
            wc1t[k * 32 + l] = Wc1[i];                 // wc1t[k][l] = Wc1[l][k]
        }
        if (threadIdx.x < 64) w2s[threadIdx.x] = Wc2[threadIdx.x];
        if (threadIdx.x < 32) bc1s[threadIdx.x] = bc1[threadIdx.x];
        if (threadIdx.x < 2)  bc2s[threadIdx.x] = bc2[threadIdx.x];
    }
    __syncthreads();

    int lane = threadIdx.x & 63;
    int wid  = (blockIdx.x * blockDim.x + threadIdx.x) >> 6;
    int nw   = (gridDim.x * blockDim.x) >> 6;
    for (int node = wid; node < n; node += nw) {
        int ro = rowptr[node], re = rowptr[node + 1];
        // gather-sum neighbors (4-way unrolled for memory-level parallelism)
        float acc = 0.f;
        int i = ro;
        for (; i + 4 <= re; i += 4) {
            int s0 = adj[i + 0], s1 = adj[i + 1], s2 = adj[i + 2], s3 = adj[i + 3];
            float v0 = x[(size_t)s0 * D + lane];
            float v1 = x[(size_t)s1 * D + lane];
            float v2 = x[(size_t)s2 * D + lane];
            float v3 = x[(size_t)s3 * D + lane];
            acc += (v0 + v1) + (v2 + v3);
        }
        for (; i < re; ++i) acc += x[(size_t)adj[i] * D + lane];
        float av = acc / fmaxf((float)(re - ro), 1.0f);
        float xv = x[(size_t)node * D + lane];

        // concat-linear: sum_j = b[j] + sum_k xv_k*W[j][k] + sum_k av_k*W[j][64+k]
        float sum = bs[lane];
        #pragma unroll
        for (int k4 = 0; k4 < 16; ++k4) {
            float4 w = Wt4[k4 * 64 + lane];
            sum = fmaf(bcast(xv, 4 * k4 + 0), w.x, sum);
            sum = fmaf(bcast(xv, 4 * k4 + 1), w.y, sum);
            sum = fmaf(bcast(xv, 4 * k4 + 2), w.z, sum);
            sum = fmaf(bcast(xv, 4 * k4 + 3), w.w, sum);
        }
        #pragma unroll
        for (int k4 = 16; k4 < 32; ++k4) {
            float4 w = Wt4[k4 * 64 + lane];
            int kk = 4 * (k4 - 16);
            sum = fmaf(bcast(av, kk + 0), w.x, sum);
            sum = fmaf(bcast(av, kk + 1), w.y, sum);
            sum = fmaf(bcast(av, kk + 2), w.z, sum);
            sum = fmaf(bcast(av, kk + 3), w.w, sum);
        }
        float x2 = fmaxf(sum, 0.0f);   // ReLU

        if (!HEAD) {
            out[(size_t)node * D + lane] = x2;
        } else {
            // h[l] = relu(bc1[l] + sum_k x2_k * Wc1[l][k]), l<32 (lanes>=32 duplicate)
            int l = lane & 31;
            float h = bc1s[l];
            #pragma unroll
            for (int k = 0; k < 64; ++k)
                h = fmaf(bcast(x2, k), wc1t[k * 32 + l], h);
            h = fmaxf(h, 0.0f);
            float p0 = (lane < 32) ? h * w2s[l]      : 0.0f;
            float p1 = (lane < 32) ? h * w2s[32 + l] : 0.0f;
            #pragma unroll
            for (int off = 1; off < 64; off <<= 1) {
                p0 += __shfl_xor(p0, off, 64);
                p1 += __shfl_xor(p1, off, 64);
            }
            if (lane == 0) {
                out[(size_t)node * 2 + 0] = p0 + bc2s[0];
                out[(size_t)node * 2 + 1] = p1 + bc2s[1];
            }
        }
    }
}

extern "C" void kernel_launch(void* const* d_in, const int* in_sizes, int n_in,
                              void* d_out, int out_size, void* d_ws, size_t ws_size,
                              hipStream_t stream)
{
    const float* feat = (const float*)d_in[0];
    const int*   eidx = (const int*)d_in[1];
    const float* W1   = (const float*)d_in[2];
    const float* b1   = (const float*)d_in[3];
    const float* W2   = (const float*)d_in[4];
    const float* b2   = (const float*)d_in[5];
    const float* Wc1  = (const float*)d_in[6];
    const float* bc1  = (const float*)d_in[7];
    const float* Wc2  = (const float*)d_in[8];
    const float* bc2  = (const float*)d_in[9];

    int n = in_sizes[0] / D;    // 100000
    int E = in_sizes[1] / 2;    // 1600000
    const int* src = eidx;
    const int* dst = eidx + E;

    // workspace layout (all 4B-aligned)
    int*   cnt      = (int*)d_ws;                       // [n]
    int*   partials = cnt + n;                          // [NB_SCAN] (pad 128)
    int*   blockoff = partials + 128;                   // [128]
    int*   rowptr   = blockoff + 128;                   // [n+1]
    int*   cursor   = rowptr + n + 1;                   // [n]
    int*   adj      = cursor + n;                       // [E]
    float* x1       = (float*)(adj + E);                // [n*64]

    int nb = (n + TSCAN - 1) / TSCAN;                   // 98

    // CSR build (reused by both layers)
    hipMemsetAsync(cnt, 0, (size_t)n * sizeof(int), stream);
    hist_kernel<<<6250, 256, 0, stream>>>(dst, cnt, E);
    partial_kernel<<<nb, TSCAN, 0, stream>>>(cnt, partials, n);
    scanp_kernel<<<1, 128, 0, stream>>>(partials, blockoff, nb);
    rowptr_kernel<<<nb, TSCAN, 0, stream>>>(cnt, blockoff, rowptr, cursor, n);
    fill_kernel<<<6250, 256, 0, stream>>>(src, dst, cursor, adj, E);

    // Layer 1: x1 = relu(SAGE(feat))
    size_t lds1 = (8192 + 64) * sizeof(float);
    sage_kernel<false><<<12500, 512, lds1, stream>>>(
        feat, rowptr, adj, W1, b1, nullptr, nullptr, nullptr, nullptr, x1, n);

    // Layer 2 + classifier head fused: d_out = head(relu(SAGE(x1)))
    size_t lds2 = (8192 + 64 + 2048 + 64 + 32 + 2) * sizeof(float);
    sage_kernel<true><<<12500, 512, lds2, stream>>>(
        x1, rowptr, adj, W2, b2, Wc1, bc1, Wc2, bc2, (float*)d_out, n);
}

// Round 3
// 917.731 us; speedup vs baseline: 1.0717x; 1.0717x over previous
//
#include <hip/hip_runtime.h>

#define D 64
#define TSCAN 1024

__device__ __forceinline__ float bcast(float v, int l) {
    return __uint_as_float(__builtin_amdgcn_readlane(__float_as_uint(v), l));
}

// ---------- CSR build ----------
__global__ void __launch_bounds__(256) hist_kernel(
    const int* __restrict__ dst, int* __restrict__ cnt, int E)
{
    int t = blockIdx.x * blockDim.x + threadIdx.x;
    int st = gridDim.x * blockDim.x;
    for (int e = t; e < E; e += st) atomicAdd(&cnt[dst[e]], 1);
}

__global__ void __launch_bounds__(TSCAN) partial_kernel(
    const int* __restrict__ cnt, int* __restrict__ partials, int n)
{
    __shared__ int red[TSCAN];
    int i = blockIdx.x * TSCAN + threadIdx.x;
    red[threadIdx.x] = (i < n) ? cnt[i] : 0;
    __syncthreads();
    for (int off = TSCAN / 2; off > 0; off >>= 1) {
        if (threadIdx.x < off) red[threadIdx.x] += red[threadIdx.x + off];
        __syncthreads();
    }
    if (threadIdx.x == 0) partials[blockIdx.x] = red[0];
}

__global__ void __launch_bounds__(128) scanp_kernel(
    const int* __restrict__ partials, int* __restrict__ blockoff, int nb)
{
    __shared__ int s[128];
    int t = threadIdx.x;
    int orig = (t < nb) ? partials[t] : 0;
    s[t] = orig;
    __syncthreads();
    for (int off = 1; off < 128; off <<= 1) {
        int v = (t >= off) ? s[t - off] : 0;
        __syncthreads();
        s[t] += v;
        __syncthreads();
    }
    if (t < nb) blockoff[t] = s[t] - orig;   // exclusive
}

__global__ void __launch_bounds__(TSCAN) rowptr_kernel(
    const int* __restrict__ cnt, const int* __restrict__ blockoff,
    int* __restrict__ rowptr, int* __restrict__ cursor, int n)
{
    __shared__ int s[TSCAN];
    int b = blockIdx.x;
    int i = b * TSCAN + threadIdx.x;
    int v = (i < n) ? cnt[i] : 0;
    s[threadIdx.x] = v;
    __syncthreads();
    for (int off = 1; off < TSCAN; off <<= 1) {
        int x = (threadIdx.x >= off) ? s[threadIdx.x - off] : 0;
        __syncthreads();
        s[threadIdx.x] += x;
        __syncthreads();
    }
    if (i < n) {
        int excl = blockoff[b] + s[threadIdx.x] - v;
        rowptr[i] = excl;
        cursor[i] = excl;
        if (i == n - 1) rowptr[n] = excl + v;
    }
}

__global__ void __launch_bounds__(256) fill_kernel(
    const int* __restrict__ src, const int* __restrict__ dst,
    int* __restrict__ cursor, int* __restrict__ adj, int E)
{
    int t = blockIdx.x * blockDim.x + threadIdx.x;
    int st = gridDim.x * blockDim.x;
    for (int e = t; e < E; e += st) {
        int p = atomicAdd(&cursor[dst[e]], 1);
        adj[p] = src[e];
    }
}

// ---------- fused SAGE layer: gather-mean + concat-linear (+ optional head) ----------
// Persistent-ish blocks: each block stages W once, waves grid-stride over nodes.
// Wave per node; lane j owns feature/output channel j.
template <bool HEAD>
__global__ void __launch_bounds__(512, 4) sage_kernel(
    const float* __restrict__ x,       // [n, 64]
    const int*   __restrict__ rowptr,  // [n+1]
    const int*   __restrict__ adj,     // [E]
    const float* __restrict__ W,       // [64, 128] row-major
    const float* __restrict__ b,       // [64]
    const float* __restrict__ Wc1,     // [32, 64]  (HEAD only)
    const float* __restrict__ bc1,     // [32]
    const float* __restrict__ Wc2,     // [2, 32]
    const float* __restrict__ bc2,     // [2]
    float*       __restrict__ out,     // HEAD ? [n,2] : [n,64]
    int n)
{
    extern __shared__ float smem[];
    float4* Wt4 = (float4*)smem;               // 8192 floats: Wt4[k4*64+j] = W[j][4k4..4k4+3]
    float*  Wt  = smem;
    float*  bs  = smem + 8192;                 // 64
    float*  wc1t = bs + 64;                    // 2048 (HEAD): wc1t[k*32+l] = Wc1[l][k]
    float*  w2s  = wc1t + 2048;                // 64
    float*  bc1s = w2s + 64;                   // 32
    float*  bc2s = bc1s + 32;                  // 2

    // Dest-indexed staging: consecutive threads write consecutive LDS words
    // (conflict-free); scattered reads of the 32KB L2-hot W are cheap.
    for (int d = threadIdx.x; d < 64 * 128; d += blockDim.x) {
        int k4 = d >> 8;           // which float4-group of k
        int j  = (d >> 2) & 63;    // output channel
        int kk = d & 3;
        Wt[d] = W[j * 128 + k4 * 4 + kk];
    }
    if (threadIdx.x < 64) bs[threadIdx.x] = b[threadIdx.x];
    if (HEAD) {
        for (int d = threadIdx.x; d < 32 * 64; d += blockDim.x) {
            int k = d >> 5, l = d & 31;
            wc1t[d] = Wc1[l * 64 + k];
        }
        if (threadIdx.x < 64) w2s[threadIdx.x] = Wc2[threadIdx.x];
        if (threadIdx.x < 32) bc1s[threadIdx.x] = bc1[threadIdx.x];
        if (threadIdx.x < 2)  bc2s[threadIdx.x] = bc2[threadIdx.x];
    }
    __syncthreads();

    int lane = threadIdx.x & 63;
    int wid  = (blockIdx.x * blockDim.x + threadIdx.x) >> 6;
    int nw   = (gridDim.x * blockDim.x) >> 6;
    for (int node = wid; node < n; node += nw) {
        int ro = rowptr[node], re = rowptr[node + 1];
        // gather-sum neighbors: 8 independent loads in flight, 2 accumulators
        float acc0 = 0.f, acc1 = 0.f;
        int i = ro;
        for (; i + 8 <= re; i += 8) {
            int s0 = adj[i+0], s1 = adj[i+1], s2 = adj[i+2], s3 = adj[i+3];
            int s4 = adj[i+4], s5 = adj[i+5], s6 = adj[i+6], s7 = adj[i+7];
            float v0 = x[(size_t)s0 * D + lane];
            float v1 = x[(size_t)s1 * D + lane];
            float v2 = x[(size_t)s2 * D + lane];
            float v3 = x[(size_t)s3 * D + lane];
            float v4 = x[(size_t)s4 * D + lane];
            float v5 = x[(size_t)s5 * D + lane];
            float v6 = x[(size_t)s6 * D + lane];
            float v7 = x[(size_t)s7 * D + lane];
            acc0 += (v0 + v1) + (v2 + v3);
            acc1 += (v4 + v5) + (v6 + v7);
        }
        for (; i < re; ++i) acc0 += x[(size_t)adj[i] * D + lane];
        float acc = acc0 + acc1;
        float av = acc / fmaxf((float)(re - ro), 1.0f);
        float xv = x[(size_t)node * D + lane];

        // concat-linear: sum_j = b[j] + sum_k xv_k*W[j][k] + sum_k av_k*W[j][64+k]
        float sum = bs[lane];
        #pragma unroll
        for (int k4 = 0; k4 < 16; ++k4) {
            float4 w = Wt4[k4 * 64 + lane];
            sum = fmaf(bcast(xv, 4 * k4 + 0), w.x, sum);
            sum = fmaf(bcast(xv, 4 * k4 + 1), w.y, sum);
            sum = fmaf(bcast(xv, 4 * k4 + 2), w.z, sum);
            sum = fmaf(bcast(xv, 4 * k4 + 3), w.w, sum);
        }
        #pragma unroll
        for (int k4 = 16; k4 < 32; ++k4) {
            float4 w = Wt4[k4 * 64 + lane];
            int kk = 4 * (k4 - 16);
            sum = fmaf(bcast(av, kk + 0), w.x, sum);
            sum = fmaf(bcast(av, kk + 1), w.y, sum);
            sum = fmaf(bcast(av, kk + 2), w.z, sum);
            sum = fmaf(bcast(av, kk + 3), w.w, sum);
        }
        float x2 = fmaxf(sum, 0.0f);   // ReLU

        if (!HEAD) {
            out[(size_t)node * D + lane] = x2;
        } else {
            // h[l] = relu(bc1[l] + sum_k x2_k * Wc1[l][k]); lanes 32-63 duplicate l=lane&31
            int l = lane & 31;
            float h = bc1s[l];
            #pragma unroll
            for (int k = 0; k < 64; ++k)
                h = fmaf(bcast(x2, k), wc1t[k * 32 + l], h);
            h = fmaxf(h, 0.0f);
            float p0 = (lane < 32) ? h * w2s[l]      : 0.0f;
            float p1 = (lane < 32) ? h * w2s[32 + l] : 0.0f;
            #pragma unroll
            for (int off = 1; off < 64; off <<= 1) {
                p0 += __shfl_xor(p0, off, 64);
                p1 += __shfl_xor(p1, off, 64);
            }
            if (lane == 0) {
                out[(size_t)node * 2 + 0] = p0 + bc2s[0];
                out[(size_t)node * 2 + 1] = p1 + bc2s[1];
            }
        }
    }
}

extern "C" void kernel_launch(void* const* d_in, const int* in_sizes, int n_in,
                              void* d_out, int out_size, void* d_ws, size_t ws_size,
                              hipStream_t stream)
{
    const float* feat = (const float*)d_in[0];
    const int*   eidx = (const int*)d_in[1];
    const float* W1   = (const float*)d_in[2];
    const float* b1   = (const float*)d_in[3];
    const float* W2   = (const float*)d_in[4];
    const float* b2   = (const float*)d_in[5];
    const float* Wc1  = (const float*)d_in[6];
    const float* bc1  = (const float*)d_in[7];
    const float* Wc2  = (const float*)d_in[8];
    const float* bc2  = (const float*)d_in[9];

    int n = in_sizes[0] / D;    // 100000
    int E = in_sizes[1] / 2;    // 1600000
    const int* src = eidx;
    const int* dst = eidx + E;

    // workspace layout (all 4B-aligned)
    int*   cnt      = (int*)d_ws;                       // [n]
    int*   partials = cnt + n;                          // [128]
    int*   blockoff = partials + 128;                   // [128]
    int*   rowptr   = blockoff + 128;                   // [n+1]
    int*   cursor   = rowptr + n + 1;                   // [n]
    int*   adj      = cursor + n;                       // [E]
    float* x1       = (float*)(adj + E);                // [n*64]

    int nb = (n + TSCAN - 1) / TSCAN;                   // 98

    // CSR build (reused by both layers)
    hipMemsetAsync(cnt, 0, (size_t)n * sizeof(int), stream);
    hist_kernel<<<6250, 256, 0, stream>>>(dst, cnt, E);
    partial_kernel<<<nb, TSCAN, 0, stream>>>(cnt, partials, n);
    scanp_kernel<<<1, 128, 0, stream>>>(partials, blockoff, nb);
    rowptr_kernel<<<nb, TSCAN, 0, stream>>>(cnt, blockoff, rowptr, cursor, n);
    fill_kernel<<<6250, 256, 0, stream>>>(src, dst, cursor, adj, E);

    // Persistent-style grid: 512 blocks x 512 thr = 4096 waves, ~24 nodes/wave;
    // 2 blocks/CU resident at VGPR<=128 -> staging paid once per ~24 nodes.
    // Layer 1: x1 = relu(SAGE(feat))
    size_t lds1 = (8192 + 64) * sizeof(float);
    sage_kernel<false><<<512, 512, lds1, stream>>>(
        feat, rowptr, adj, W1, b1, nullptr, nullptr, nullptr, nullptr, x1, n);

    // Layer 2 + classifier head fused: d_out = head(relu(SAGE(x1)))
    size_t lds2 = (8192 + 64 + 2048 + 64 + 32 + 2) * sizeof(float);
    sage_kernel<true><<<512, 512, lds2, stream>>>(
        x1, rowptr, adj, W2, b2, Wc1, bc1, Wc2, bc2, (float*)d_out, n);
}